// Round 1
// baseline (129.664 us; speedup 1.0000x reference)
//
#include <hip/hip_runtime.h>
#include <math.h>
#include <stdint.h>

#define NIMG 8
#define HH 1024
#define WW 1024
#define NPIX (HH*WW)
#define PAIRS 10000

// ws layout (40 uint/float slots):
// [0..7] edgemax bits, [8..15] maxdiff bits, [16..23] valid counts (uint),
// [24..31] eqsum (float), [32..39] uneqsum (float)

__device__ __forceinline__ uint64_t mix64(uint64_t x){
    x += 0x9E3779B97F4A7C15ull;
    x = (x ^ (x >> 30)) * 0xBF58476D1CE4E5B9ull;
    x = (x ^ (x >> 27)) * 0x94D049BB133111EBull;
    return x ^ (x >> 31);
}

__device__ __forceinline__ void sobel_at(const float* __restrict__ x, int r, int c,
                                         float& gx, float& gy){
    const float* p0 = x + (size_t)(r-1)*WW + c;
    const float* p1 = x + (size_t)r*WW + c;
    const float* p2 = x + (size_t)(r+1)*WW + c;
    float a = p0[-1], b = p0[0], cc = p0[1];
    float d = p1[-1],             e = p1[1];
    float f = p2[-1], g = p2[0], h = p2[1];
    gx = (cc - a) + 2.0f*(e - d) + (h - f);
    gy = (a + 2.0f*b + cc) - (f + 2.0f*g + h);
}

__global__ void init_ws_kernel(unsigned int* __restrict__ ws){
    int t = threadIdx.x;
    if (t < 40) ws[t] = 0u;
}

__global__ void edgemax_kernel(const float* __restrict__ images,
                               unsigned int* __restrict__ edgemax){
    int img = blockIdx.y;
    const float* x = images + (size_t)img * 3 * NPIX;   // channel 0
    float m = 0.0f;
    for (int r = 1 + blockIdx.x; r < HH-1; r += gridDim.x){
        for (int c = 1 + threadIdx.x; c < WW-1; c += blockDim.x){
            float gx, gy;
            sobel_at(x, r, c, gx, gy);
            m = fmaxf(m, sqrtf(gx*gx + gy*gy));
        }
    }
    for (int off = 32; off; off >>= 1)
        m = fmaxf(m, __shfl_down(m, off));
    if ((threadIdx.x & 63) == 0)
        atomicMax(&edgemax[img], __float_as_uint(m));
}

template<int PASS>
__global__ void sample_kernel(const float* __restrict__ inputs,
                              const float* __restrict__ targets,
                              const float* __restrict__ images,
                              const float* __restrict__ depth_gt,
                              const unsigned int* __restrict__ edgemax,
                              unsigned int* __restrict__ maxdiff,
                              unsigned int* __restrict__ counts,
                              float* __restrict__ eqsum,
                              float* __restrict__ uneqsum){
    int img = blockIdx.y;
    int j = blockIdx.x * blockDim.x + threadIdx.x;
    const float* x   = images   + (size_t)img * 3 * NPIX;  // ch0
    const float* inp = inputs   + (size_t)img * NPIX;
    const float* tgt = targets  + (size_t)img * NPIX;
    const float* dgt = depth_gt + (size_t)img * NPIX;

    float edgethr = 0.1f * __uint_as_float(edgemax[img]);

    float mdiff = 0.0f;           // pass1 local max
    float s_eq = 0.0f, s_un = 0.0f;
    unsigned int cnt = 0;

    if (j < PAIRS){
        uint64_t base = ((uint64_t)(img * PAIRS + j)) << 10;
        bool pdir = (mix64(((uint64_t)(NIMG * PAIRS + img)) << 10) & 1ull) != 0ull;

        int sh = -1, sw = -1;
        float gxs = 0.0f, gys = 0.0f;
        for (int att = 0; att < 900; ++att){
            uint64_t u = mix64(base + (uint64_t)att);
            uint32_t pix = (uint32_t)(u >> 44);        // exact 20-bit uniform
            int r = (int)(pix >> 10);
            int c = (int)(pix & (WW - 1));
            if (r == 0 || r >= HH-1 || c == 0 || c >= WW-1) continue;
            float gx, gy;
            sobel_at(x, r, c, gx, gy);
            float e = sqrtf(gx*gx + gy*gy);
            if (!(e >= edgethr)) continue;
            float dg = dgt[r*WW + c];
            float tg = tgt[r*WW + c];
            if (!(dg > -0.001f && dg < 80.0f && tg != 80.0f)) continue;
            sh = r; sw = c; gxs = gx; gys = gy;
            break;
        }

        if (sh >= 0){
            float th = atan2f(gys, gxs);
            float cmul, rmul;
            if (pdir){
                cmul = cosf(th); rmul = sinf(th);
            } else {
                // th2 = (th + pi/2 + pi) mod 2pi - pi ; col uses sin(th2), row uses cos(th2)
                float th2 = fmodf(th + 4.71238898038469f, 6.283185307179586f)
                            - 3.14159265358979323846f;
                cmul = sinf(th2); rmul = cosf(th2);
            }
            uint64_t u0 = mix64(base + 1000ull);
            uint64_t u1 = mix64(base + 1001ull);
            float dist[4];
            dist[0] = -(float)(2u + (uint32_t)(u0 & 0xFFFFFFFFull) % 29u);
            dist[1] = -(float)(2u + (uint32_t)(u0 >> 32) % 29u);
            dist[2] =  (float)(2u + (uint32_t)(u1 & 0xFFFFFFFFull) % 29u);
            dist[3] =  (float)(2u + (uint32_t)(u1 >> 32) % 29u);

            int rowc[4], colc[4];
            bool valid = true;
            #pragma unroll
            for (int k = 0; k < 4; ++k){
                int cc2 = sw + (int)rintf(dist[k] * cmul);
                int rr2 = sh + (int)rintf(dist[k] * rmul);
                if (cc2 < 0 || cc2 > WW-1 || rr2 < 0 || rr2 > HH-1) valid = false;
                colc[k] = min(max(cc2, 0), WW-1);
                rowc[k] = min(max(rr2, 0), HH-1);
            }

            if (valid){
                if (PASS == 1){
                    #pragma unroll
                    for (int k = 0; k < 3; ++k){
                        float tA = tgt[rowc[k]*WW + colc[k]];
                        float tB = tgt[rowc[k+1]*WW + colc[k+1]];
                        mdiff = fmaxf(mdiff, fabsf(tA - tB));
                    }
                    cnt = 3;
                } else {
                    float md = __uint_as_float(maxdiff[img]);
                    float inv = 1.0f / (md + 1e-6f);
                    #pragma unroll
                    for (int k = 0; k < 3; ++k){
                        int pA = rowc[k]*WW + colc[k];
                        int pB = rowc[k+1]*WW + colc[k+1];
                        float tA = tgt[pA], tB = tgt[pB];
                        float ratio = (tA + 1e-6f) / (tB + 1e-6f);
                        float ad = fabsf(tA - tB);
                        bool eq = (ratio < 1.03f) && (ratio > 0.9708737864077669f);
                        float iA = inp[pA], iB = inp[pB];
                        if (eq){
                            float tw = expf(ad * inv);
                            float d = iA - iB;
                            s_eq += d*d / tw;
                        } else {
                            float lab = (ratio >= 1.03f) ? 1.0f : -1.0f;
                            float xarg = (iB - iA) * lab;
                            s_un += log1pf(expf(xarg));
                        }
                    }
                }
            }
        }
    }

    // wave-level reduction (wave = 64 lanes)
    if (PASS == 1){
        for (int off = 32; off; off >>= 1){
            mdiff = fmaxf(mdiff, __shfl_down(mdiff, off));
            cnt  += __shfl_down(cnt, off);
        }
        if ((threadIdx.x & 63) == 0){
            atomicMax(&maxdiff[img], __float_as_uint(mdiff));
            atomicAdd(&counts[img], cnt);
        }
    } else {
        for (int off = 32; off; off >>= 1){
            s_eq += __shfl_down(s_eq, off);
            s_un += __shfl_down(s_un, off);
        }
        if ((threadIdx.x & 63) == 0){
            atomicAdd(&eqsum[img], s_eq);
            atomicAdd(&uneqsum[img], s_un);
        }
    }
}

__global__ void finalize_kernel(const unsigned int* __restrict__ counts,
                                const float* __restrict__ eqsum,
                                const float* __restrict__ uneqsum,
                                float* __restrict__ out){
    float tl = 0.0f, tc = 0.0f;
    for (int i = 0; i < NIMG; ++i){
        float cnt = (float)counts[i];
        float c = fmaxf(cnt, 1.0f);
        tl += (eqsum[i] + uneqsum[i]) / c;   // ALPHA = 1
        tc += cnt;
    }
    out[0] = tl / (float)NIMG;
    out[1] = tc / (float)NIMG;
}

extern "C" void kernel_launch(void* const* d_in, const int* in_sizes, int n_in,
                              void* d_out, int out_size, void* d_ws, size_t ws_size,
                              hipStream_t stream) {
    const float* inputs  = (const float*)d_in[0];
    const float* targets = (const float*)d_in[1];
    const float* images  = (const float*)d_in[2];
    const float* depth   = (const float*)d_in[3];
    float* out = (float*)d_out;

    unsigned int* ws      = (unsigned int*)d_ws;
    unsigned int* edgemax = ws;
    unsigned int* maxdiff = ws + 8;
    unsigned int* counts  = ws + 16;
    float* eqsum          = (float*)(ws + 24);
    float* unsum          = (float*)(ws + 32);

    hipLaunchKernelGGL(init_ws_kernel, dim3(1), dim3(64), 0, stream, ws);
    hipLaunchKernelGGL(edgemax_kernel, dim3(128, NIMG), dim3(256), 0, stream,
                       images, edgemax);
    dim3 sgrid((PAIRS + 255) / 256, NIMG);
    hipLaunchKernelGGL((sample_kernel<1>), sgrid, dim3(256), 0, stream,
                       inputs, targets, images, depth, edgemax, maxdiff, counts,
                       eqsum, unsum);
    hipLaunchKernelGGL((sample_kernel<2>), sgrid, dim3(256), 0, stream,
                       inputs, targets, images, depth, edgemax, maxdiff, counts,
                       eqsum, unsum);
    hipLaunchKernelGGL(finalize_kernel, dim3(1), dim3(1), 0, stream,
                       counts, eqsum, unsum, out);
}

// Round 2
// 79.747 us; speedup vs baseline: 1.6260x; 1.6260x over previous
//
#include <hip/hip_runtime.h>
#include <math.h>
#include <stdint.h>

#define NIMG 8
#define HH 1024
#define WW 1024
#define NPIX (HH*WW)
#define PAIRS 10000
#define STRIP 8

// ws layout:
// [0..7]   edgemax bits (max SQUARED sobel magnitude, float as uint)
// [8..15]  maxdiff bits (float as uint)
// [16..23] valid counts (uint)
// [24..31] eqsum (float)
// [32..39] uneqsum (float)
// byte 256 ..: uint4 records [NIMG*PAIRS]

__device__ __forceinline__ uint64_t mix64(uint64_t x){
    x += 0x9E3779B97F4A7C15ull;
    x = (x ^ (x >> 30)) * 0xBF58476D1CE4E5B9ull;
    x = (x ^ (x >> 27)) * 0x94D049BB133111EBull;
    return x ^ (x >> 31);
}

__device__ __forceinline__ void sobel_at(const float* __restrict__ x, int r, int c,
                                         float& gx, float& gy){
    const float* p0 = x + (size_t)(r-1)*WW + c;
    const float* p1 = x + (size_t)r*WW + c;
    const float* p2 = x + (size_t)(r+1)*WW + c;
    float a = p0[-1], b = p0[0], cc = p0[1];
    float d = p1[-1],             e = p1[1];
    float f = p2[-1], g = p2[0], h = p2[1];
    gx = (cc - a) + 2.0f*(e - d) + (h - f);
    gy = (a + 2.0f*b + cc) - (f + 2.0f*g + h);
}

__device__ __forceinline__ void load16(const float* __restrict__ p, float* d){
    const float4* q = (const float4*)p;
    float4 v0 = q[0], v1 = q[1], v2 = q[2], v3 = q[3];
    d[0]=v0.x; d[1]=v0.y; d[2]=v0.z; d[3]=v0.w;
    d[4]=v1.x; d[5]=v1.y; d[6]=v1.z; d[7]=v1.w;
    d[8]=v2.x; d[9]=v2.y; d[10]=v2.z; d[11]=v2.w;
    d[12]=v3.x; d[13]=v3.y; d[14]=v3.z; d[15]=v3.w;
}

// One wave owns a full 1024-wide row span (16 cols/lane). Rolls 3 rows in
// registers; separable sobel (sx = a+2b+n for gx, dy = a-n for gy); cross-lane
// column neighbors via shuffles. Tracks max of SQUARED magnitude (sqrt-free).
__global__ __launch_bounds__(256) void edgemax_kernel(const float* __restrict__ images,
                                                      unsigned int* __restrict__ edgemax){
    int img  = blockIdx.y;
    const float* x = images + (size_t)img * 3 * NPIX;   // channel 0
    int wv   = threadIdx.x >> 6;
    int lane = threadIdx.x & 63;
    int strip = blockIdx.x * 4 + wv;                    // 0..127
    int r0 = 1 + strip * STRIP;
    int r1 = min(r0 + STRIP - 1, HH - 2);
    int c0 = lane * 16;

    float a[16], b[16], n[16];
    load16(x + (size_t)(r0-1)*WW + c0, a);
    load16(x + (size_t)r0*WW + c0, b);

    float m = 0.0f;
    for (int r = r0; r <= r1; ++r){
        load16(x + (size_t)(r+1)*WW + c0, n);
        float sx[16], dy[16];
        #pragma unroll
        for (int i = 0; i < 16; ++i){
            sx[i] = a[i] + 2.0f*b[i] + n[i];
            dy[i] = a[i] - n[i];
        }
        float sxl = __shfl_up(sx[15], 1);
        float sxr = __shfl_down(sx[0], 1);
        float dyl = __shfl_up(dy[15], 1);
        float dyr = __shfl_down(dy[0], 1);
        #pragma unroll
        for (int j = 0; j < 16; ++j){
            float sl = (j == 0)  ? sxl : sx[j-1];
            float sr = (j == 15) ? sxr : sx[j+1];
            float dl = (j == 0)  ? dyl : dy[j-1];
            float dr = (j == 15) ? dyr : dy[j+1];
            float gx = sr - sl;
            float gy = dl + 2.0f*dy[j] + dr;
            float e2 = gx*gx + gy*gy;
            int c = c0 + j;
            if (c >= 1 && c <= WW-2) m = fmaxf(m, e2);
        }
        #pragma unroll
        for (int i = 0; i < 16; ++i){ a[i] = b[i]; b[i] = n[i]; }
    }
    for (int off = 32; off; off >>= 1)
        m = fmaxf(m, __shfl_down(m, off));
    if (lane == 0)
        atomicMax(&edgemax[img], __float_as_uint(m));
}

struct Sample {
    int valid;
    int rowc[4], colc[4];
};

__device__ __forceinline__ Sample draw_sample(int img, int j,
        const float* __restrict__ x, const float* __restrict__ tgt,
        const float* __restrict__ dgt, float thr2){
    Sample s;
    s.valid = 0;
    #pragma unroll
    for (int k = 0; k < 4; ++k){ s.rowc[k] = 0; s.colc[k] = 0; }

    uint64_t base = ((uint64_t)(img * PAIRS + j)) << 10;
    bool pdir = (mix64(((uint64_t)(NIMG * PAIRS + img)) << 10) & 1ull) != 0ull;

    int sh = -1, sw = -1;
    float gxs = 0.0f, gys = 0.0f, e2s = 1.0f;
    for (int att = 0; att < 900; ++att){
        uint64_t u = mix64(base + (uint64_t)att);
        uint32_t pix = (uint32_t)(u >> 44);           // 20-bit uniform
        int r = (int)(pix >> 10);
        int c = (int)(pix & (WW - 1));
        if (r == 0 || r >= HH-1 || c == 0 || c >= WW-1) continue;
        float gx, gy;
        sobel_at(x, r, c, gx, gy);
        float e2 = gx*gx + gy*gy;
        if (!(e2 >= thr2)) continue;
        float dg = dgt[r*WW + c];
        float tg = tgt[r*WW + c];
        if (!(dg > -0.001f && dg < 80.0f && tg != 80.0f)) continue;
        sh = r; sw = c; gxs = gx; gys = gy; e2s = e2;
        break;
    }
    if (sh < 0) return s;

    // cos(theta)=gx/e, sin(theta)=gy/e ; pdir=false: cmul=-cos, rmul=sin
    float inv = rsqrtf(e2s);
    float cmul = gxs * inv;
    float rmul = gys * inv;
    if (!pdir) cmul = -cmul;

    uint64_t u0 = mix64(base + 1000ull);
    uint64_t u1 = mix64(base + 1001ull);
    float dist[4];
    dist[0] = -(float)(2u + (uint32_t)(u0 & 0xFFFFFFFFull) % 29u);
    dist[1] = -(float)(2u + (uint32_t)(u0 >> 32) % 29u);
    dist[2] =  (float)(2u + (uint32_t)(u1 & 0xFFFFFFFFull) % 29u);
    dist[3] =  (float)(2u + (uint32_t)(u1 >> 32) % 29u);

    bool valid = true;
    #pragma unroll
    for (int k = 0; k < 4; ++k){
        int cc2 = sw + (int)rintf(dist[k] * cmul);
        int rr2 = sh + (int)rintf(dist[k] * rmul);
        if (cc2 < 0 || cc2 > WW-1 || rr2 < 0 || rr2 > HH-1) valid = false;
        s.colc[k] = min(max(cc2, 0), WW-1);
        s.rowc[k] = min(max(rr2, 0), HH-1);
    }
    s.valid = valid ? 1 : 0;
    return s;
}

template<int USEREC>
__global__ void sample1_kernel(const float* __restrict__ targets,
                               const float* __restrict__ images,
                               const float* __restrict__ depth_gt,
                               const unsigned int* __restrict__ edgemax,
                               unsigned int* __restrict__ maxdiff,
                               unsigned int* __restrict__ counts,
                               uint4* __restrict__ recs){
    int img = blockIdx.y;
    int j = blockIdx.x * blockDim.x + threadIdx.x;
    const float* x   = images   + (size_t)img * 3 * NPIX;
    const float* tgt = targets  + (size_t)img * NPIX;
    const float* dgt = depth_gt + (size_t)img * NPIX;

    float mdiff = 0.0f;
    unsigned int cnt = 0;

    if (j < PAIRS){
        float thr2 = 0.01f * __uint_as_float(edgemax[img]);
        Sample s = draw_sample(img, j, x, tgt, dgt, thr2);
        if (USEREC){
            uint4 rec = make_uint4(0xFFFFFFFFu, 0u, 0u, 0u);
            if (s.valid){
                rec.x = ((unsigned)s.rowc[0] << 16) | (unsigned)s.colc[0];
                rec.y = ((unsigned)s.rowc[1] << 16) | (unsigned)s.colc[1];
                rec.z = ((unsigned)s.rowc[2] << 16) | (unsigned)s.colc[2];
                rec.w = ((unsigned)s.rowc[3] << 16) | (unsigned)s.colc[3];
            }
            recs[img * PAIRS + j] = rec;
        }
        if (s.valid){
            #pragma unroll
            for (int k = 0; k < 3; ++k){
                float tA = tgt[s.rowc[k]*WW + s.colc[k]];
                float tB = tgt[s.rowc[k+1]*WW + s.colc[k+1]];
                mdiff = fmaxf(mdiff, fabsf(tA - tB));
            }
            cnt = 3;
        }
    }

    for (int off = 32; off; off >>= 1){
        mdiff = fmaxf(mdiff, __shfl_down(mdiff, off));
        cnt  += __shfl_down(cnt, off);
    }
    if ((threadIdx.x & 63) == 0){
        atomicMax(&maxdiff[img], __float_as_uint(mdiff));
        atomicAdd(&counts[img], cnt);
    }
}

template<int USEREC>
__global__ void sample2_kernel(const float* __restrict__ inputs,
                               const float* __restrict__ targets,
                               const float* __restrict__ images,
                               const float* __restrict__ depth_gt,
                               const unsigned int* __restrict__ edgemax,
                               const unsigned int* __restrict__ maxdiff,
                               const uint4* __restrict__ recs,
                               float* __restrict__ eqsum,
                               float* __restrict__ uneqsum){
    int img = blockIdx.y;
    int j = blockIdx.x * blockDim.x + threadIdx.x;
    const float* inp = inputs   + (size_t)img * NPIX;
    const float* tgt = targets  + (size_t)img * NPIX;

    float s_eq = 0.0f, s_un = 0.0f;

    if (j < PAIRS){
        int rowc[4], colc[4];
        bool valid;
        if (USEREC){
            uint4 rec = recs[img * PAIRS + j];
            valid = (rec.x != 0xFFFFFFFFu);
            rowc[0] = rec.x >> 16; colc[0] = rec.x & 0xFFFF;
            rowc[1] = rec.y >> 16; colc[1] = rec.y & 0xFFFF;
            rowc[2] = rec.z >> 16; colc[2] = rec.z & 0xFFFF;
            rowc[3] = rec.w >> 16; colc[3] = rec.w & 0xFFFF;
        } else {
            const float* x   = images   + (size_t)img * 3 * NPIX;
            const float* dgt = depth_gt + (size_t)img * NPIX;
            float thr2 = 0.01f * __uint_as_float(edgemax[img]);
            Sample s = draw_sample(img, j, x, tgt, dgt, thr2);
            valid = (s.valid != 0);
            #pragma unroll
            for (int k = 0; k < 4; ++k){ rowc[k] = s.rowc[k]; colc[k] = s.colc[k]; }
        }

        if (valid){
            float md = __uint_as_float(maxdiff[img]);
            float inv = 1.0f / (md + 1e-6f);
            #pragma unroll
            for (int k = 0; k < 3; ++k){
                int pA = rowc[k]*WW + colc[k];
                int pB = rowc[k+1]*WW + colc[k+1];
                float tA = tgt[pA], tB = tgt[pB];
                float ratio = (tA + 1e-6f) / (tB + 1e-6f);
                float ad = fabsf(tA - tB);
                bool eq = (ratio < 1.03f) && (ratio > 0.9708737864077669f);
                float iA = inp[pA], iB = inp[pB];
                if (eq){
                    float tw = expf(ad * inv);
                    float d = iA - iB;
                    s_eq += d*d / tw;
                } else {
                    float lab = (ratio >= 1.03f) ? 1.0f : -1.0f;
                    float xarg = (iB - iA) * lab;
                    s_un += log1pf(expf(xarg));
                }
            }
        }
    }

    for (int off = 32; off; off >>= 1){
        s_eq += __shfl_down(s_eq, off);
        s_un += __shfl_down(s_un, off);
    }
    if ((threadIdx.x & 63) == 0){
        atomicAdd(&eqsum[img], s_eq);
        atomicAdd(&uneqsum[img], s_un);
    }
}

__global__ void finalize_kernel(const unsigned int* __restrict__ counts,
                                const float* __restrict__ eqsum,
                                const float* __restrict__ uneqsum,
                                float* __restrict__ out){
    float tl = 0.0f, tc = 0.0f;
    for (int i = 0; i < NIMG; ++i){
        float cnt = (float)counts[i];
        float c = fmaxf(cnt, 1.0f);
        tl += (eqsum[i] + uneqsum[i]) / c;   // ALPHA = 1
        tc += cnt;
    }
    out[0] = tl / (float)NIMG;
    out[1] = tc / (float)NIMG;
}

extern "C" void kernel_launch(void* const* d_in, const int* in_sizes, int n_in,
                              void* d_out, int out_size, void* d_ws, size_t ws_size,
                              hipStream_t stream) {
    const float* inputs  = (const float*)d_in[0];
    const float* targets = (const float*)d_in[1];
    const float* images  = (const float*)d_in[2];
    const float* depth   = (const float*)d_in[3];
    float* out = (float*)d_out;

    unsigned int* ws      = (unsigned int*)d_ws;
    unsigned int* edgemax = ws;
    unsigned int* maxdiff = ws + 8;
    unsigned int* counts  = ws + 16;
    float* eqsum          = (float*)(ws + 24);
    float* unsum          = (float*)(ws + 32);
    uint4* recs           = (uint4*)((char*)d_ws + 256);
    bool userec = ws_size >= 256 + (size_t)NIMG * PAIRS * sizeof(uint4);

    hipMemsetAsync(d_ws, 0, 40 * sizeof(unsigned int), stream);
    hipLaunchKernelGGL(edgemax_kernel, dim3(32, NIMG), dim3(256), 0, stream,
                       images, edgemax);
    dim3 sgrid((PAIRS + 255) / 256, NIMG);
    if (userec){
        hipLaunchKernelGGL((sample1_kernel<1>), sgrid, dim3(256), 0, stream,
                           targets, images, depth, edgemax, maxdiff, counts, recs);
        hipLaunchKernelGGL((sample2_kernel<1>), sgrid, dim3(256), 0, stream,
                           inputs, targets, images, depth, edgemax, maxdiff, recs,
                           eqsum, unsum);
    } else {
        hipLaunchKernelGGL((sample1_kernel<0>), sgrid, dim3(256), 0, stream,
                           targets, images, depth, edgemax, maxdiff, counts, recs);
        hipLaunchKernelGGL((sample2_kernel<0>), sgrid, dim3(256), 0, stream,
                           inputs, targets, images, depth, edgemax, maxdiff, recs,
                           eqsum, unsum);
    }
    hipLaunchKernelGGL(finalize_kernel, dim3(1), dim3(1), 0, stream,
                       counts, eqsum, unsum, out);
}

// Round 3
// 56.124 us; speedup vs baseline: 2.3103x; 1.4209x over previous
//
#include <hip/hip_runtime.h>
#include <math.h>
#include <stdint.h>

#define NIMG 8
#define HH 1024
#define WW 1024
#define NPIX (HH*WW)
#define PAIRS 10000
#define STRIP 8
#define NSTRIPS 128          // strips per image (rows 1..1022, 8 rows each)
#define S1BLOCKS 40          // ceil(PAIRS/256)
#define WSLOTS (S1BLOCKS*4)  // per-wave partial slots per image (160)

// ws layout (floats, all plain stores — no init needed, fully overwritten per launch):
// [0                 .. NIMG*NSTRIPS)                edgepart (squared sobel max per strip)
// [1024              .. 1024+NIMG*WSLOTS)            md_part
// [2304              .. 2304+NIMG*WSLOTS)            cnt_part
// [3584              .. 3584+NIMG*WSLOTS)            eq_part
// [4864              .. 4864+NIMG*WSLOTS)            un_part
// byte 65536 ..: uint4 records [NIMG*PAIRS]
#define OFF_EDGE 0
#define OFF_MD   1024
#define OFF_CNT  2304
#define OFF_EQ   3584
#define OFF_UN   4864

__device__ __forceinline__ uint64_t mix64(uint64_t x){
    x += 0x9E3779B97F4A7C15ull;
    x = (x ^ (x >> 30)) * 0xBF58476D1CE4E5B9ull;
    x = (x ^ (x >> 27)) * 0x94D049BB133111EBull;
    return x ^ (x >> 31);
}

__device__ __forceinline__ float block_reduce_max(float v, float* sm){
    for (int off = 32; off; off >>= 1)
        v = fmaxf(v, __shfl_down(v, off));
    int wv = threadIdx.x >> 6, lane = threadIdx.x & 63;
    int nw = blockDim.x >> 6;
    if (lane == 0) sm[wv] = v;
    __syncthreads();
    if (threadIdx.x == 0){
        float m = sm[0];
        for (int i = 1; i < nw; ++i) m = fmaxf(m, sm[i]);
        sm[0] = m;
    }
    __syncthreads();
    float r = sm[0];
    __syncthreads();
    return r;
}

__device__ __forceinline__ float block_reduce_sum(float v, float* sm){
    for (int off = 32; off; off >>= 1)
        v += __shfl_down(v, off);
    int wv = threadIdx.x >> 6, lane = threadIdx.x & 63;
    int nw = blockDim.x >> 6;
    if (lane == 0) sm[wv] = v;
    __syncthreads();
    if (threadIdx.x == 0){
        float m = sm[0];
        for (int i = 1; i < nw; ++i) m += sm[i];
        sm[0] = m;
    }
    __syncthreads();
    float r = sm[0];
    __syncthreads();
    return r;
}

__device__ __forceinline__ void sobel_at(const float* __restrict__ x, int r, int c,
                                         float& gx, float& gy){
    const float* p0 = x + (size_t)(r-1)*WW + c;
    const float* p1 = x + (size_t)r*WW + c;
    const float* p2 = x + (size_t)(r+1)*WW + c;
    float a = p0[-1], b = p0[0], cc = p0[1];
    float d = p1[-1],             e = p1[1];
    float f = p2[-1], g = p2[0], h = p2[1];
    gx = (cc - a) + 2.0f*(e - d) + (h - f);
    gy = (a + 2.0f*b + cc) - (f + 2.0f*g + h);
}

__device__ __forceinline__ void load16(const float* __restrict__ p, float* d){
    const float4* q = (const float4*)p;
    float4 v0 = q[0], v1 = q[1], v2 = q[2], v3 = q[3];
    d[0]=v0.x; d[1]=v0.y; d[2]=v0.z; d[3]=v0.w;
    d[4]=v1.x; d[5]=v1.y; d[6]=v1.z; d[7]=v1.w;
    d[8]=v2.x; d[9]=v2.y; d[10]=v2.z; d[11]=v2.w;
    d[12]=v3.x; d[13]=v3.y; d[14]=v3.z; d[15]=v3.w;
}

// One wave owns a 1024-wide row span (16 cols/lane), rolls 3 rows in registers,
// separable sobel, cross-lane neighbors via shuffles, max of SQUARED magnitude.
// Per-strip partial max stored with a plain store (no atomics, no init).
__global__ __launch_bounds__(256) void edgemax_kernel(const float* __restrict__ images,
                                                      float* __restrict__ edgepart){
    int img  = blockIdx.y;
    const float* x = images + (size_t)img * 3 * NPIX;   // channel 0
    int wv   = threadIdx.x >> 6;
    int lane = threadIdx.x & 63;
    int strip = blockIdx.x * 4 + wv;                    // 0..127
    int r0 = 1 + strip * STRIP;
    int r1 = min(r0 + STRIP - 1, HH - 2);
    int c0 = lane * 16;

    float a[16], b[16], n[16];
    load16(x + (size_t)(r0-1)*WW + c0, a);
    load16(x + (size_t)r0*WW + c0, b);

    float m = 0.0f;
    for (int r = r0; r <= r1; ++r){
        load16(x + (size_t)(r+1)*WW + c0, n);
        float sx[16], dy[16];
        #pragma unroll
        for (int i = 0; i < 16; ++i){
            sx[i] = a[i] + 2.0f*b[i] + n[i];
            dy[i] = a[i] - n[i];
        }
        float sxl = __shfl_up(sx[15], 1);
        float sxr = __shfl_down(sx[0], 1);
        float dyl = __shfl_up(dy[15], 1);
        float dyr = __shfl_down(dy[0], 1);
        #pragma unroll
        for (int j = 0; j < 16; ++j){
            float sl = (j == 0)  ? sxl : sx[j-1];
            float sr = (j == 15) ? sxr : sx[j+1];
            float dl = (j == 0)  ? dyl : dy[j-1];
            float dr = (j == 15) ? dyr : dy[j+1];
            float gx = sr - sl;
            float gy = dl + 2.0f*dy[j] + dr;
            float e2 = gx*gx + gy*gy;
            int c = c0 + j;
            if (c >= 1 && c <= WW-2) m = fmaxf(m, e2);
        }
        #pragma unroll
        for (int i = 0; i < 16; ++i){ a[i] = b[i]; b[i] = n[i]; }
    }
    for (int off = 32; off; off >>= 1)
        m = fmaxf(m, __shfl_down(m, off));
    if (lane == 0)
        edgepart[img * NSTRIPS + strip] = m;
}

struct Sample {
    int valid;
    int rowc[4], colc[4];
};

__device__ __forceinline__ Sample draw_sample(int img, int j,
        const float* __restrict__ x, const float* __restrict__ tgt,
        const float* __restrict__ dgt, float thr2){
    Sample s;
    s.valid = 0;
    #pragma unroll
    for (int k = 0; k < 4; ++k){ s.rowc[k] = 0; s.colc[k] = 0; }

    uint64_t base = ((uint64_t)(img * PAIRS + j)) << 10;
    bool pdir = (mix64(((uint64_t)(NIMG * PAIRS + img)) << 10) & 1ull) != 0ull;

    int sh = -1, sw = -1;
    float gxs = 0.0f, gys = 0.0f, e2s = 1.0f;
    for (int att = 0; att < 900; ++att){
        uint64_t u = mix64(base + (uint64_t)att);
        uint32_t pix = (uint32_t)(u >> 44);           // 20-bit uniform
        int r = (int)(pix >> 10);
        int c = (int)(pix & (WW - 1));
        if (r == 0 || r >= HH-1 || c == 0 || c >= WW-1) continue;
        float gx, gy;
        sobel_at(x, r, c, gx, gy);
        float e2 = gx*gx + gy*gy;
        if (!(e2 >= thr2)) continue;
        float dg = dgt[r*WW + c];
        float tg = tgt[r*WW + c];
        if (!(dg > -0.001f && dg < 80.0f && tg != 80.0f)) continue;
        sh = r; sw = c; gxs = gx; gys = gy; e2s = e2;
        break;
    }
    if (sh < 0) return s;

    // cos(theta)=gx/e, sin(theta)=gy/e ; pdir=false: cmul=-cos, rmul=sin
    float inv = rsqrtf(e2s);
    float cmul = gxs * inv;
    float rmul = gys * inv;
    if (!pdir) cmul = -cmul;

    uint64_t u0 = mix64(base + 1000ull);
    uint64_t u1 = mix64(base + 1001ull);
    float dist[4];
    dist[0] = -(float)(2u + (uint32_t)(u0 & 0xFFFFFFFFull) % 29u);
    dist[1] = -(float)(2u + (uint32_t)(u0 >> 32) % 29u);
    dist[2] =  (float)(2u + (uint32_t)(u1 & 0xFFFFFFFFull) % 29u);
    dist[3] =  (float)(2u + (uint32_t)(u1 >> 32) % 29u);

    bool valid = true;
    #pragma unroll
    for (int k = 0; k < 4; ++k){
        int cc2 = sw + (int)rintf(dist[k] * cmul);
        int rr2 = sh + (int)rintf(dist[k] * rmul);
        if (cc2 < 0 || cc2 > WW-1 || rr2 < 0 || rr2 > HH-1) valid = false;
        s.colc[k] = min(max(cc2, 0), WW-1);
        s.rowc[k] = min(max(rr2, 0), HH-1);
    }
    s.valid = valid ? 1 : 0;
    return s;
}

template<int USEREC>
__global__ __launch_bounds__(256) void sample1_kernel(
                               const float* __restrict__ targets,
                               const float* __restrict__ images,
                               const float* __restrict__ depth_gt,
                               float* __restrict__ ws,
                               uint4* __restrict__ recs){
    __shared__ float sred[4];
    int img = blockIdx.y;
    int j = blockIdx.x * blockDim.x + threadIdx.x;
    const float* x   = images   + (size_t)img * 3 * NPIX;
    const float* tgt = targets  + (size_t)img * NPIX;
    const float* dgt = depth_gt + (size_t)img * NPIX;

    // thr2 from edge partials (plain loads, block-wide reduce)
    float v = 0.0f;
    if (threadIdx.x < NSTRIPS) v = ws[OFF_EDGE + img * NSTRIPS + threadIdx.x];
    float thr2 = 0.01f * block_reduce_max(v, sred);

    float mdiff = 0.0f;
    float cnt = 0.0f;

    if (j < PAIRS){
        Sample s = draw_sample(img, j, x, tgt, dgt, thr2);
        if (USEREC){
            uint4 rec = make_uint4(0xFFFFFFFFu, 0u, 0u, 0u);
            if (s.valid){
                rec.x = ((unsigned)s.rowc[0] << 16) | (unsigned)s.colc[0];
                rec.y = ((unsigned)s.rowc[1] << 16) | (unsigned)s.colc[1];
                rec.z = ((unsigned)s.rowc[2] << 16) | (unsigned)s.colc[2];
                rec.w = ((unsigned)s.rowc[3] << 16) | (unsigned)s.colc[3];
            }
            recs[img * PAIRS + j] = rec;
        }
        if (s.valid){
            #pragma unroll
            for (int k = 0; k < 3; ++k){
                float tA = tgt[s.rowc[k]*WW + s.colc[k]];
                float tB = tgt[s.rowc[k+1]*WW + s.colc[k+1]];
                mdiff = fmaxf(mdiff, fabsf(tA - tB));
            }
            cnt = 3.0f;
        }
    }

    for (int off = 32; off; off >>= 1){
        mdiff = fmaxf(mdiff, __shfl_down(mdiff, off));
        cnt  += __shfl_down(cnt, off);
    }
    if ((threadIdx.x & 63) == 0){
        int slot = blockIdx.x * 4 + (threadIdx.x >> 6);
        ws[OFF_MD  + img * WSLOTS + slot] = mdiff;
        ws[OFF_CNT + img * WSLOTS + slot] = cnt;
    }
}

template<int USEREC>
__global__ __launch_bounds__(256) void sample2_kernel(
                               const float* __restrict__ inputs,
                               const float* __restrict__ targets,
                               const float* __restrict__ images,
                               const float* __restrict__ depth_gt,
                               float* __restrict__ ws,
                               const uint4* __restrict__ recs){
    __shared__ float sred[4];
    int img = blockIdx.y;
    int j = blockIdx.x * blockDim.x + threadIdx.x;
    const float* inp = inputs   + (size_t)img * NPIX;
    const float* tgt = targets  + (size_t)img * NPIX;

    // maxdiff from sample1 partials
    float v = 0.0f;
    if (threadIdx.x < WSLOTS) v = ws[OFF_MD + img * WSLOTS + threadIdx.x];
    float md = block_reduce_max(v, sred);
    float inv = 1.0f / (md + 1e-6f);

    float thr2 = 0.0f;
    if (!USEREC){
        float e = 0.0f;
        if (threadIdx.x < NSTRIPS) e = ws[OFF_EDGE + img * NSTRIPS + threadIdx.x];
        thr2 = 0.01f * block_reduce_max(e, sred);
    }

    float s_eq = 0.0f, s_un = 0.0f;

    if (j < PAIRS){
        int rowc[4], colc[4];
        bool valid;
        if (USEREC){
            uint4 rec = recs[img * PAIRS + j];
            valid = (rec.x != 0xFFFFFFFFu);
            rowc[0] = rec.x >> 16; colc[0] = rec.x & 0xFFFF;
            rowc[1] = rec.y >> 16; colc[1] = rec.y & 0xFFFF;
            rowc[2] = rec.z >> 16; colc[2] = rec.z & 0xFFFF;
            rowc[3] = rec.w >> 16; colc[3] = rec.w & 0xFFFF;
        } else {
            const float* x   = images   + (size_t)img * 3 * NPIX;
            const float* dgt = depth_gt + (size_t)img * NPIX;
            Sample s = draw_sample(img, j, x, tgt, dgt, thr2);
            valid = (s.valid != 0);
            #pragma unroll
            for (int k = 0; k < 4; ++k){ rowc[k] = s.rowc[k]; colc[k] = s.colc[k]; }
        }

        if (valid){
            #pragma unroll
            for (int k = 0; k < 3; ++k){
                int pA = rowc[k]*WW + colc[k];
                int pB = rowc[k+1]*WW + colc[k+1];
                float tA = tgt[pA], tB = tgt[pB];
                float ratio = (tA + 1e-6f) / (tB + 1e-6f);
                float ad = fabsf(tA - tB);
                bool eq = (ratio < 1.03f) && (ratio > 0.9708737864077669f);
                float iA = inp[pA], iB = inp[pB];
                if (eq){
                    float tw = expf(ad * inv);
                    float d = iA - iB;
                    s_eq += d*d / tw;
                } else {
                    float lab = (ratio >= 1.03f) ? 1.0f : -1.0f;
                    float xarg = (iB - iA) * lab;
                    s_un += log1pf(expf(xarg));
                }
            }
        }
    }

    for (int off = 32; off; off >>= 1){
        s_eq += __shfl_down(s_eq, off);
        s_un += __shfl_down(s_un, off);
    }
    if ((threadIdx.x & 63) == 0){
        int slot = blockIdx.x * 4 + (threadIdx.x >> 6);
        ws[OFF_EQ + img * WSLOTS + slot] = s_eq;
        ws[OFF_UN + img * WSLOTS + slot] = s_un;
    }
}

__global__ __launch_bounds__(256) void finalize_kernel(const float* __restrict__ ws,
                                                       float* __restrict__ out){
    __shared__ float sred[4];
    float tl = 0.0f, tc = 0.0f;
    for (int img = 0; img < NIMG; ++img){
        float c_ = 0.0f, e_ = 0.0f, u_ = 0.0f;
        if (threadIdx.x < WSLOTS){
            c_ = ws[OFF_CNT + img * WSLOTS + threadIdx.x];
            e_ = ws[OFF_EQ  + img * WSLOTS + threadIdx.x];
            u_ = ws[OFF_UN  + img * WSLOTS + threadIdx.x];
        }
        float cnt = block_reduce_sum(c_, sred);
        float eq  = block_reduce_sum(e_, sred);
        float un  = block_reduce_sum(u_, sred);
        tl += (eq + un) / fmaxf(cnt, 1.0f);   // ALPHA = 1
        tc += cnt;
    }
    if (threadIdx.x == 0){
        out[0] = tl / (float)NIMG;
        out[1] = tc / (float)NIMG;
    }
}

extern "C" void kernel_launch(void* const* d_in, const int* in_sizes, int n_in,
                              void* d_out, int out_size, void* d_ws, size_t ws_size,
                              hipStream_t stream) {
    const float* inputs  = (const float*)d_in[0];
    const float* targets = (const float*)d_in[1];
    const float* images  = (const float*)d_in[2];
    const float* depth   = (const float*)d_in[3];
    float* out = (float*)d_out;

    float* ws   = (float*)d_ws;
    uint4* recs = (uint4*)((char*)d_ws + 65536);
    bool userec = ws_size >= 65536 + (size_t)NIMG * PAIRS * sizeof(uint4);

    hipLaunchKernelGGL(edgemax_kernel, dim3(NSTRIPS/4, NIMG), dim3(256), 0, stream,
                       images, ws + OFF_EDGE);
    dim3 sgrid(S1BLOCKS, NIMG);
    if (userec){
        hipLaunchKernelGGL((sample1_kernel<1>), sgrid, dim3(256), 0, stream,
                           targets, images, depth, ws, recs);
        hipLaunchKernelGGL((sample2_kernel<1>), sgrid, dim3(256), 0, stream,
                           inputs, targets, images, depth, ws, recs);
    } else {
        hipLaunchKernelGGL((sample1_kernel<0>), sgrid, dim3(256), 0, stream,
                           targets, images, depth, ws, recs);
        hipLaunchKernelGGL((sample2_kernel<0>), sgrid, dim3(256), 0, stream,
                           inputs, targets, images, depth, ws, recs);
    }
    hipLaunchKernelGGL(finalize_kernel, dim3(1), dim3(256), 0, stream, ws, out);
}